// Round 9
// baseline (282.229 us; speedup 1.0000x reference)
//
#include <hip/hip_runtime.h>

#define NB 10
#define BLOCK 256
#define GRID 2048
#define SSTRIDE (GRID * BLOCK)

// R8 lesson: all-loads-up-front creates a device-level convoy (all waves load,
// then all compute; phases serialize: ~40us mem + ~30us valu ~= 76us observed).
// R9: register double-buffer pipeline - prefetch batch k+1's 8 nt loads BEFORE
// computing batch k, so memory stays busy during compute. 4 batches of 4
// vec4-pairs per thread; flush packed accumulators every 2 batches (32 elems).
// Accumulators in packed registers (R2/R3: no LDS ops in hot loop):
//  cnt64/lab64: 10 x 6-bit fields (<=32/flush < 63 for any distribution)
//  rA,rB: 5+5 x 12-bit fixed-point r=round((10*conf-b)*63) (<=2016 < 4095)
// Reconstruction: conf_sum = (b*cnt + rsum/63)/10; quant err ~8e-4 << 4.8e-2.

typedef float vfloat4 __attribute__((ext_vector_type(4)));
typedef int   vint4   __attribute__((ext_vector_type(4)));

__device__ __forceinline__ void acc_one(float xx, unsigned ll,
                                        unsigned long long& cnt64,
                                        unsigned long long& lab64,
                                        unsigned long long& rA,
                                        unsigned long long& rB) {
    float e = __expf(-xx);
    float t = __builtin_amdgcn_rcpf(__builtin_fmaf(e, 0.1f, 0.1f));  // 10*sigmoid(x)
    int b = (int)t;                        // t>=0 so trunc==floor
    b = min(b, NB - 1);
    float r = t - floorf(t);               // v_fract_f32
    unsigned rfix = (unsigned)__builtin_fmaf(r, 63.0f, 0.5f);
    int s6 = b * 6;
    cnt64 += 1ULL << s6;
    lab64 += (unsigned long long)ll << s6;
    bool hi = b >= 5;
    int s12 = (hi ? b - 5 : b) * 12;
    unsigned long long val = (unsigned long long)rfix << s12;
    rA += hi ? 0ULL : val;
    rB += hi ? val : 0ULL;
}

__device__ __forceinline__ void flush_packed(unsigned long long& cnt64,
                                             unsigned long long& lab64,
                                             unsigned long long& rA,
                                             unsigned long long& rB,
                                             unsigned* cl, unsigned* ru) {
#pragma unroll
    for (int i = 0; i < NB; ++i) {
        unsigned c = (unsigned)((cnt64 >> (6 * i)) & 63ULL);
        unsigned l = (unsigned)((lab64 >> (6 * i)) & 63ULL);
        cl[i] += c | (l << 16);
    }
#pragma unroll
    for (int i = 0; i < 5; ++i) {
        ru[i]     += (unsigned)((rA >> (12 * i)) & 4095ULL);
        ru[5 + i] += (unsigned)((rB >> (12 * i)) & 4095ULL);
    }
    cnt64 = 0ULL; lab64 = 0ULL; rA = 0ULL; rB = 0ULL;
}

__global__ __launch_bounds__(BLOCK, 4) void ece_partial(const float* __restrict__ logits,
                                                        const int* __restrict__ labels,
                                                        unsigned int* __restrict__ ws,
                                                        int n, int wstride) {
    const int tid = threadIdx.x;
    const int gtid = blockIdx.x * BLOCK + tid;
    const int n4 = n >> 2;
    const vfloat4* __restrict__ l4 = (const vfloat4*)logits;
    const vint4*   __restrict__ b4 = (const vint4*)labels;

    unsigned cl[NB], ru[NB];
#pragma unroll
    for (int i = 0; i < NB; ++i) { cl[i] = 0u; ru[i] = 0u; }

    if (n4 == 16 * SSTRIDE) {
        // fast path (N=2^25): 16 vec4/thread, 4 batches of 4 vec4-pairs,
        // double-buffered so 8 nt loads are ALWAYS in flight during compute.
        vfloat4 xb[2][4];
        vint4   yb[2][4];
#pragma unroll
        for (int j = 0; j < 4; ++j) {
            xb[0][j] = __builtin_nontemporal_load(&l4[gtid + j * SSTRIDE]);
            yb[0][j] = __builtin_nontemporal_load(&b4[gtid + j * SSTRIDE]);
        }
        unsigned long long cnt64 = 0ULL, lab64 = 0ULL, rA = 0ULL, rB = 0ULL;
#pragma unroll
        for (int it = 0; it < 4; ++it) {
            const int cur = it & 1, nxt = cur ^ 1;
            if (it < 3) {
#pragma unroll
                for (int j = 0; j < 4; ++j) {
                    xb[nxt][j] = __builtin_nontemporal_load(&l4[gtid + ((it + 1) * 4 + j) * SSTRIDE]);
                    yb[nxt][j] = __builtin_nontemporal_load(&b4[gtid + ((it + 1) * 4 + j) * SSTRIDE]);
                }
            }
#pragma unroll
            for (int j = 0; j < 4; ++j) {
#pragma unroll
                for (int k = 0; k < 4; ++k)
                    acc_one(xb[cur][j][k], (unsigned)yb[cur][j][k], cnt64, lab64, rA, rB);
            }
            if (it & 1) flush_packed(cnt64, lab64, rA, rB, cl, ru);  // every 32 elems
        }
    } else {
        // generic fallback (never taken for N=2^25)
        for (int v = gtid; v < n4; v += SSTRIDE) {
            unsigned long long cnt64 = 0ULL, lab64 = 0ULL, rA = 0ULL, rB = 0ULL;
            vfloat4 x = __builtin_nontemporal_load(&l4[v]);
            vint4   y = __builtin_nontemporal_load(&b4[v]);
#pragma unroll
            for (int k = 0; k < 4; ++k)
                acc_one(x[k], (unsigned)y[k], cnt64, lab64, rA, rB);
            flush_packed(cnt64, lab64, rA, rB, cl, ru);
        }
        if (gtid == 0 && (n & 3)) {
            unsigned long long cnt64 = 0ULL, lab64 = 0ULL, rA = 0ULL, rB = 0ULL;
            for (int j2 = n4 * 4; j2 < n; ++j2)
                acc_one(logits[j2], (unsigned)labels[j2], cnt64, lab64, rA, rB);
            flush_packed(cnt64, lab64, rA, rB, cl, ru);
        }
    }

    // Wave shuffle reduce (exact integer math; cnt per thread <= 64 ->
    // 64-lane halfword sums < 2^13; ru < 64*4032 << 2^32).
#pragma unroll
    for (int i = 0; i < NB; ++i) {
#pragma unroll
        for (int off = 32; off > 0; off >>= 1) {
            cl[i] += __shfl_down(cl[i], off, 64);
            ru[i] += __shfl_down(ru[i], off, 64);
        }
    }

    __shared__ unsigned red[4][2 * NB];
    const int wave = tid >> 6, lane = tid & 63;
    if (lane == 0) {
#pragma unroll
        for (int i = 0; i < NB; ++i) { red[wave][i] = cl[i]; red[wave][NB + i] = ru[i]; }
    }
    __syncthreads();
    if (tid < 2 * NB) {
        unsigned s = red[0][tid] + red[1][tid] + red[2][tid] + red[3][tid];
        if (tid < NB) {
            atomicAdd(&ws[tid * wstride], s & 0xffffu);       // counts -> 0..9
            atomicAdd(&ws[(NB + tid) * wstride], s >> 16);    // labels -> 10..19
        } else {
            atomicAdd(&ws[(NB + tid) * wstride], s);          // rsum   -> 20..29
        }
    }
}

__global__ void ece_final(const unsigned int* __restrict__ ws, float* __restrict__ out,
                          int wstride) {
    if (threadIdx.x == 0 && blockIdx.x == 0) {
        float ece = 0.0f, mx = 0.0f;
        for (int b = 0; b < NB; ++b) {
            unsigned cnt = ws[b * wstride];
            unsigned lab = ws[(NB + b) * wstride];
            unsigned rs  = ws[(2 * NB + b) * wstride];
            float pos = 0.0f, cfb = 0.0f, e = 0.0f;
            if (cnt > 0u) {
                float inv = 1.0f / (float)cnt;
                pos = (float)lab * inv;
                cfb = ((float)b + (float)rs * (1.0f / 63.0f) * inv) * 0.1f;
                e = fabsf(pos - cfb);
            }
            out[b] = pos;
            out[NB + b] = cfb;
            ece += e;
            mx = fmaxf(mx, e);
        }
        out[2 * NB] = ece;
        out[2 * NB + 1] = mx;
    }
}

extern "C" void kernel_launch(void* const* d_in, const int* in_sizes, int n_in,
                              void* d_out, int out_size, void* d_ws, size_t ws_size,
                              hipStream_t stream) {
    const float* logits = (const float*)d_in[0];
    const int*   labels = (const int*)d_in[1];
    float* out = (float*)d_out;
    unsigned int* ws = (unsigned int*)d_ws;
    int n = in_sizes[0];

    int wstride = (ws_size >= 30 * 16 * sizeof(unsigned)) ? 16 : 1;
    hipMemsetAsync(d_ws, 0, (size_t)(30 * wstride) * sizeof(unsigned), stream);

    ece_partial<<<GRID, BLOCK, 0, stream>>>(logits, labels, ws, n, wstride);
    ece_final<<<1, 64, 0, stream>>>(ws, out, wstride);
}